// Round 1
// baseline (4060.607 us; speedup 1.0000x reference)
//
#include <hip/hip_runtime.h>
#include <hip/hip_bf16.h>
#include <math.h>

#define N_NODES 8000
#define N_EDGES 256000
#define NSTEPS 10

// rotated LDS addressing: row r, col e (0..63). Conflict-free for both
// (consecutive-k, fixed-e) staging writes and (fixed-k, lane=e) compute reads.
__device__ __forceinline__ int rot(int r, int e) { return r * 64 + ((e + r) & 63); }

__global__ __launch_bounds__(256)
void prep_edges_k(const float* __restrict__ J, const float* __restrict__ b,
                  const int* __restrict__ row, const int* __restrict__ col,
                  float* __restrict__ Jv, float* __restrict__ brv, float* __restrict__ bcv) {
    int idx = blockIdx.x * 256 + threadIdx.x;
    if (idx < N_EDGES) {
        int r = row[idx], c = col[idx];
        Jv[idx]  = J[(long)r * N_NODES + c];
        brv[idx] = b[r];
        bcv[idx] = b[c];
    }
}

// out[k*O + j] = in[j*K + k]  for in of shape [O,K] row-major
__global__ __launch_bounds__(256)
void transpose_k(const float* __restrict__ in, float* __restrict__ out, int O, int K) {
    int idx = blockIdx.x * 256 + threadIdx.x;
    if (idx < O * K) {
        int j = idx / K, k = idx - j * K;
        out[k * O + j] = in[idx];
    }
}

// Edge message MLP (3 layers) + segment-sum scatter into nm.
// 64 edges per block, 256 threads (4 waves). lane = edge, 32 neurons per lane.
__global__ __launch_bounds__(256)
void msg_mlp_k(const float* __restrict__ h,
               const int* __restrict__ row, const int* __restrict__ col,
               const float* __restrict__ Jv, const float* __restrict__ brv,
               const float* __restrict__ bcv,
               const float* __restrict__ W1t, const float* __restrict__ bm1,
               const float* __restrict__ W2t, const float* __restrict__ bm2,
               const float* __restrict__ W3t, const float* __restrict__ bm3,
               float* __restrict__ nm) {
    __shared__ float em_s[128 * 64];   // em rows 0..127 (h[row]|h[col]); later reused for t2
    __shared__ float t1_s[128 * 64];   // layer1 output; later reused for m
    const int tid  = threadIdx.x;
    const int e0   = blockIdx.x * 64;
    const int lane = tid & 63;
    const int w    = tid >> 6;

    // stage h[row[e]] and h[col[e]] (coalesced global reads, rotated LDS writes)
    for (int idx = tid; idx < 64 * 64; idx += 256) {
        int e = idx >> 6, k = idx & 63;
        int r = row[e0 + e];        // wave-uniform -> scalar load
        int c = col[e0 + e];
        em_s[rot(k, e)]      = h[r * 64 + k];
        em_s[rot(64 + k, e)] = h[c * 64 + k];
    }
    // per-edge scalars stay in registers (em rows 128..130)
    float jv = Jv[e0 + lane], bv = brv[e0 + lane], cv = bcv[e0 + lane];
    __syncthreads();

    const int j0 = __builtin_amdgcn_readfirstlane(w * 32);
    float acc[32];

    // ---- layer 1: [131] -> [128], relu ----
    #pragma unroll
    for (int jj = 0; jj < 32; jj++) acc[jj] = bm1[j0 + jj];
    for (int k = 0; k < 128; k++) {
        float ev = em_s[rot(k, lane)];
        const float* wr = W1t + k * 128 + j0;
        #pragma unroll
        for (int jj = 0; jj < 32; jj++) acc[jj] = fmaf(ev, wr[jj], acc[jj]);
    }
    {
        const float* w128 = W1t + 128 * 128 + j0;
        const float* w129 = W1t + 129 * 128 + j0;
        const float* w130 = W1t + 130 * 128 + j0;
        #pragma unroll
        for (int jj = 0; jj < 32; jj++)
            acc[jj] += jv * w128[jj] + bv * w129[jj] + cv * w130[jj];
    }
    #pragma unroll
    for (int jj = 0; jj < 32; jj++) t1_s[rot(j0 + jj, lane)] = fmaxf(acc[jj], 0.f);
    __syncthreads();

    // ---- layer 2: [128] -> [128], relu (t2 written into em_s region) ----
    #pragma unroll
    for (int jj = 0; jj < 32; jj++) acc[jj] = bm2[j0 + jj];
    for (int k = 0; k < 128; k++) {
        float ev = t1_s[rot(k, lane)];
        const float* wr = W2t + k * 128 + j0;
        #pragma unroll
        for (int jj = 0; jj < 32; jj++) acc[jj] = fmaf(ev, wr[jj], acc[jj]);
    }
    __syncthreads();  // all waves done reading em_s(layer1 input) before overwrite? (they were after layer1 sync; this sync orders t1 reads vs layer3 writes)
    #pragma unroll
    for (int jj = 0; jj < 32; jj++) em_s[rot(j0 + jj, lane)] = fmaxf(acc[jj], 0.f);
    __syncthreads();

    // ---- layer 3: [128] -> [64], no relu (m written into t1_s region) ----
    const int j3 = __builtin_amdgcn_readfirstlane(w * 16);
    float acc3[16];
    #pragma unroll
    for (int jj = 0; jj < 16; jj++) acc3[jj] = bm3[j3 + jj];
    for (int k = 0; k < 128; k++) {
        float ev = em_s[rot(k, lane)];
        const float* wr = W3t + k * 64 + j3;
        #pragma unroll
        for (int jj = 0; jj < 16; jj++) acc3[jj] = fmaf(ev, wr[jj], acc3[jj]);
    }
    #pragma unroll
    for (int jj = 0; jj < 16; jj++) t1_s[rot(j3 + jj, lane)] = acc3[jj];
    __syncthreads();

    // ---- scatter: rows are sorted (np.unique) -> run-accumulate, few atomics ----
    {
        int d = tid & 63, q = tid >> 6;
        int ebeg = q * 16, eend = ebeg + 16;
        float a = 0.f;
        int cur = row[e0 + ebeg];      // wave-uniform -> scalar load
        for (int e = ebeg; e < eend; e++) {
            int r = row[e0 + e];
            if (r != cur) { atomicAdd(&nm[cur * 64 + d], a); a = 0.f; cur = r; }
            a += t1_s[rot(d, e)];
        }
        atomicAdd(&nm[cur * 64 + d], a);
    }
}

// GRU cell: 4 nodes per block, thread = (node, dim)
__global__ __launch_bounds__(256)
void gru_k(const float* __restrict__ nm, const float* __restrict__ h,
           const float* __restrict__ Wiht, const float* __restrict__ Whht,
           const float* __restrict__ b_ih, const float* __restrict__ b_hh,
           float* __restrict__ hn) {
    __shared__ float nms[4][64], hs[4][64];
    int tid = threadIdx.x, g = tid >> 6, d = tid & 63;
    int n = blockIdx.x * 4 + g;
    nms[g][d] = nm[n * 64 + d];
    hs[g][d]  = h[n * 64 + d];
    __syncthreads();
    float ir = b_ih[d], iz = b_ih[64 + d], inn = b_ih[128 + d];
    float hr = b_hh[d], hz = b_hh[64 + d], hnn = b_hh[128 + d];
    for (int k = 0; k < 64; k++) {
        float nv = nms[g][k], hv = hs[g][k];
        const float* wi = Wiht + k * 192;
        const float* wh = Whht + k * 192;
        ir  = fmaf(nv, wi[d],       ir);
        iz  = fmaf(nv, wi[64 + d],  iz);
        inn = fmaf(nv, wi[128 + d], inn);
        hr  = fmaf(hv, wh[d],       hr);
        hz  = fmaf(hv, wh[64 + d],  hz);
        hnn = fmaf(hv, wh[128 + d], hnn);
    }
    float r  = 1.f / (1.f + expf(-(ir + hr)));
    float z  = 1.f / (1.f + expf(-(iz + hz)));
    float ng = tanhf(inn + r * hnn);
    hn[n * 64 + d] = (1.f - z) * ng + z * hs[g][d];
}

// Readout MLP + softmax. 4 nodes per block, 64 threads per node (one wave).
__global__ __launch_bounds__(256)
void readout_k(const float* __restrict__ h,
               const float* __restrict__ Wr1t, const float* __restrict__ br1,
               const float* __restrict__ Wr2t, const float* __restrict__ br2,
               const float* __restrict__ Wr3, const float* __restrict__ br3,
               float* __restrict__ out) {
    __shared__ float hs[4][64], r1s[4][128];
    int tid = threadIdx.x, g = tid >> 6, d = tid & 63;
    int n = blockIdx.x * 4 + g;
    hs[g][d] = h[n * 64 + d];
    __syncthreads();
    float a0 = br1[d], a1 = br1[64 + d];
    for (int k = 0; k < 64; k++) {
        float v = hs[g][k];
        a0 = fmaf(v, Wr1t[k * 128 + d],      a0);
        a1 = fmaf(v, Wr1t[k * 128 + 64 + d], a1);
    }
    r1s[g][d] = fmaxf(a0, 0.f); r1s[g][64 + d] = fmaxf(a1, 0.f);
    __syncthreads();
    a0 = br2[d]; a1 = br2[64 + d];
    for (int k = 0; k < 128; k++) {
        float v = r1s[g][k];
        a0 = fmaf(v, Wr2t[k * 128 + d],      a0);
        a1 = fmaf(v, Wr2t[k * 128 + 64 + d], a1);
    }
    float q0 = fmaxf(a0, 0.f), q1 = fmaxf(a1, 0.f);
    float p0 = q0 * Wr3[d]       + q1 * Wr3[64 + d];
    float p1 = q0 * Wr3[128 + d] + q1 * Wr3[128 + 64 + d];
    #pragma unroll
    for (int off = 32; off > 0; off >>= 1) {
        p0 += __shfl_down(p0, off);
        p1 += __shfl_down(p1, off);
    }
    if (d == 0) {
        float l0 = p0 + br3[0], l1 = p1 + br3[1];
        float mx = fmaxf(l0, l1);
        float e0v = expf(l0 - mx), e1v = expf(l1 - mx), s = e0v + e1v;
        out[n * 2 + 0] = e0v / s;
        out[n * 2 + 1] = e1v / s;
        out[2 * N_NODES + n * 2 + 0] = l0;
        out[2 * N_NODES + n * 2 + 1] = l1;
    }
}

extern "C" void kernel_launch(void* const* d_in, const int* in_sizes, int n_in,
                              void* d_out, int out_size, void* d_ws, size_t ws_size,
                              hipStream_t stream) {
    const float* J    = (const float*)d_in[0];
    const float* b    = (const float*)d_in[1];
    const int*   row  = (const int*)d_in[2];
    const int*   col  = (const int*)d_in[3];
    const float* Wm1  = (const float*)d_in[4];
    const float* bm1  = (const float*)d_in[5];
    const float* Wm2  = (const float*)d_in[6];
    const float* bm2  = (const float*)d_in[7];
    const float* Wm3  = (const float*)d_in[8];
    const float* bm3  = (const float*)d_in[9];
    const float* W_ih = (const float*)d_in[10];
    const float* W_hh = (const float*)d_in[11];
    const float* b_ih = (const float*)d_in[12];
    const float* b_hh = (const float*)d_in[13];
    const float* Wr1  = (const float*)d_in[14];
    const float* br1  = (const float*)d_in[15];
    const float* Wr2  = (const float*)d_in[16];
    const float* br2  = (const float*)d_in[17];
    const float* Wr3  = (const float*)d_in[18];
    const float* br3  = (const float*)d_in[19];
    float* out = (float*)d_out;

    float* ws  = (float*)d_ws;
    float* Jv  = ws;  ws += N_EDGES;
    float* brv = ws;  ws += N_EDGES;
    float* bcv = ws;  ws += N_EDGES;
    float* h   = ws;  ws += N_NODES * 64;
    float* hn  = ws;  ws += N_NODES * 64;
    float* nm  = ws;  ws += N_NODES * 64;
    float* W1t = ws;  ws += 131 * 128;
    float* W2t = ws;  ws += 128 * 128;
    float* W3t = ws;  ws += 128 * 64;
    float* Wiht = ws; ws += 64 * 192;
    float* Whht = ws; ws += 64 * 192;
    float* Wr1t = ws; ws += 64 * 128;
    float* Wr2t = ws; ws += 128 * 128;

    prep_edges_k<<<(N_EDGES + 255) / 256, 256, 0, stream>>>(J, b, row, col, Jv, brv, bcv);
    transpose_k<<<(128 * 131 + 255) / 256, 256, 0, stream>>>(Wm1, W1t, 128, 131);
    transpose_k<<<(128 * 128 + 255) / 256, 256, 0, stream>>>(Wm2, W2t, 128, 128);
    transpose_k<<<(64 * 128 + 255) / 256, 256, 0, stream>>>(Wm3, W3t, 64, 128);
    transpose_k<<<(192 * 64 + 255) / 256, 256, 0, stream>>>(W_ih, Wiht, 192, 64);
    transpose_k<<<(192 * 64 + 255) / 256, 256, 0, stream>>>(W_hh, Whht, 192, 64);
    transpose_k<<<(128 * 64 + 255) / 256, 256, 0, stream>>>(Wr1, Wr1t, 128, 64);
    transpose_k<<<(128 * 128 + 255) / 256, 256, 0, stream>>>(Wr2, Wr2t, 128, 128);

    hipMemsetAsync(h, 0, N_NODES * 64 * sizeof(float), stream);

    float* hc = h; float* hx = hn;
    for (int s = 0; s < NSTEPS; s++) {
        hipMemsetAsync(nm, 0, N_NODES * 64 * sizeof(float), stream);
        msg_mlp_k<<<N_EDGES / 64, 256, 0, stream>>>(hc, row, col, Jv, brv, bcv,
                                                    W1t, bm1, W2t, bm2, W3t, bm3, nm);
        gru_k<<<N_NODES / 4, 256, 0, stream>>>(nm, hc, Wiht, Whht, b_ih, b_hh, hx);
        float* t = hc; hc = hx; hx = t;
    }
    readout_k<<<N_NODES / 4, 256, 0, stream>>>(hc, Wr1t, br1, Wr2t, br2, Wr3, br3, out);
}

// Round 4
// 1450.070 us; speedup vs baseline: 2.8003x; 2.8003x over previous
//
#include <hip/hip_runtime.h>
#include <math.h>

#define N_NODES 8000
#define N_EDGES 256000
#define NSTEPS 10
#define LO_SCALE 4096.0f
#define LO_INV   (1.0f/4096.0f)

typedef unsigned short u16;
typedef _Float16 h8_t __attribute__((ext_vector_type(8)));
typedef float f32x4 __attribute__((ext_vector_type(4)));

#define MFMA(a, b, c) __builtin_amdgcn_mfma_f32_16x16x32_f16((a), (b), (c), 0, 0, 0)

// x ~= hi + lo/4096 with relative error ~2^-22 (lo scaled to stay fp16-normal)
__device__ __forceinline__ void split2(float x, u16& hi, u16& lo) {
    _Float16 h = (_Float16)x;
    _Float16 l = (_Float16)((x - (float)h) * LO_SCALE);
    hi = __builtin_bit_cast(u16, h);
    lo = __builtin_bit_cast(u16, l);
}
__device__ __forceinline__ float h2f(u16 u) {
    return (float)__builtin_bit_cast(_Float16, u);
}
__device__ __forceinline__ float joinv(u16 hi, u16 lo) {
    return h2f(hi) + h2f(lo) * LO_INV;
}

// ---------------- one-time prep kernels ----------------

// exg[e] = 8 u16: [Jv_hi, br_hi, bc_hi, 0, Jv_lo, br_lo, bc_lo, 0]
__global__ __launch_bounds__(256)
void prep_edges_k(const float* __restrict__ J, const float* __restrict__ b,
                  const int* __restrict__ row, const int* __restrict__ col,
                  u16* __restrict__ exg) {
    int idx = blockIdx.x * 256 + threadIdx.x;
    if (idx < N_EDGES) {
        int r = row[idx], c = col[idx];
        u16 jh, jl, rh, rl, ch, cl;
        split2(J[(long)r * N_NODES + c], jh, jl);
        split2(b[r], rh, rl);
        split2(b[c], ch, cl);
        uint4 v;
        v.x = (unsigned)jh | ((unsigned)rh << 16);
        v.y = (unsigned)ch;
        v.z = (unsigned)jl | ((unsigned)rl << 16);
        v.w = (unsigned)cl;
        ((uint4*)exg)[idx] = v;
    }
}

__global__ __launch_bounds__(256)
void convw_k(const float* __restrict__ Wm1, const float* __restrict__ Wm2,
             const float* __restrict__ Wm3,
             u16* __restrict__ W1m_h, u16* __restrict__ W1m_l,
             u16* __restrict__ W1x_h, u16* __restrict__ W1x_l,
             u16* __restrict__ W2_h,  u16* __restrict__ W2_l,
             u16* __restrict__ W3_h,  u16* __restrict__ W3_l) {
    int i = blockIdx.x * 256 + threadIdx.x;
    u16 hi = 0, lo = 0;
    if (i < 16384) {                       // W1 main: [128][128] (k<128)
        int j = i >> 7, k = i & 127;
        split2(Wm1[j * 131 + k], hi, lo);
        W1m_h[i] = hi; W1m_l[i] = lo;
    } else if (i < 17408) {                // W1 extras: [128][8], k=128..130 then 0
        int t = i - 16384; int j = t >> 3, k = t & 7;
        if (k < 3) split2(Wm1[j * 131 + 128 + k], hi, lo);
        W1x_h[t] = hi; W1x_l[t] = lo;
    } else if (i < 33792) {                // W2: [128][128]
        int t = i - 17408;
        split2(Wm2[t], hi, lo);
        W2_h[t] = hi; W2_l[t] = lo;
    } else if (i < 41984) {                // W3: [64][128]
        int t = i - 33792;
        split2(Wm3[t], hi, lo);
        W3_h[t] = hi; W3_l[t] = lo;
    }
}

// out[k*O + j] = in[j*K + k]
__global__ __launch_bounds__(256)
void transpose_k(const float* __restrict__ in, float* __restrict__ out, int O, int K) {
    int idx = blockIdx.x * 256 + threadIdx.x;
    if (idx < O * K) {
        int j = idx / K, k = idx - j * K;
        out[k * O + j] = in[idx];
    }
}

// ---------------- edge-message MLP via split-fp16 MFMA ----------------
// act LDS: [64][128] u16 rows (256 B), 16B chunks XOR-swizzled: chunk c of row
// e lives at chunk slot (c ^ (e&7)).  4 waves; wave w covers all 64 edges x
// neurons [w*32, w*32+32) (layers 1,2) / [w*16, w*16+16) (layer 3).
// Dual accumulators: accH = Ah*Wh (+bias), accC = Ah*Wl + Al*Wh;
// value = accH + accC/4096.

template <int NT>
__device__ __forceinline__ void layer_gemm3(const u16* Ah, const u16* Al,
                                            const u16* __restrict__ Wh,
                                            const u16* __restrict__ Wl,
                                            const float* __restrict__ bias,
                                            int wn, int l15, int g,
                                            f32x4 (&accH)[4][NT], f32x4 (&accC)[4][NT]) {
    #pragma unroll
    for (int jt = 0; jt < NT; jt++) {
        float bv = bias[wn + jt * 16 + l15];
        #pragma unroll
        for (int et = 0; et < 4; et++) {
            accH[et][jt] = f32x4{bv, bv, bv, bv};
            accC[et][jt] = f32x4{0.f, 0.f, 0.f, 0.f};
        }
    }
    #pragma unroll
    for (int k0 = 0; k0 < 4; k0++) {
        h8_t bh[NT], bl[NT], ah[4], al[4];
        #pragma unroll
        for (int jt = 0; jt < NT; jt++) {
            int off = (wn + jt * 16 + l15) * 128 + k0 * 32 + g * 8;
            bh[jt] = *(const h8_t*)(Wh + off);
            bl[jt] = *(const h8_t*)(Wl + off);
        }
        #pragma unroll
        for (int et = 0; et < 4; et++) {
            int r = et * 16 + l15;
            int off = (r * 16 + ((k0 * 4 + g) ^ (r & 7))) * 8;
            ah[et] = *(const h8_t*)(Ah + off);
            al[et] = *(const h8_t*)(Al + off);
        }
        #pragma unroll
        for (int et = 0; et < 4; et++)
            #pragma unroll
            for (int jt = 0; jt < NT; jt++) {
                accH[et][jt] = MFMA(ah[et], bh[jt], accH[et][jt]);
                accC[et][jt] = MFMA(ah[et], bl[jt], accC[et][jt]);
                accC[et][jt] = MFMA(al[et], bh[jt], accC[et][jt]);
            }
    }
}

__device__ __forceinline__ void write_act2(u16* Bh, u16* Bl,
                                           f32x4 (&accH)[4][2], f32x4 (&accC)[4][2],
                                           int wn, int l15, int g) {
    #pragma unroll
    for (int et = 0; et < 4; et++)
        #pragma unroll
        for (int jt = 0; jt < 2; jt++) {
            int j = wn + jt * 16 + l15;
            int c = j >> 3, jl = j & 7;
            #pragma unroll
            for (int r = 0; r < 4; r++) {
                int e = et * 16 + g * 4 + r;
                float y = fmaxf(accH[et][jt][r] + accC[et][jt][r] * LO_INV, 0.f);
                u16 hi, lo; split2(y, hi, lo);
                int idx = e * 128 + ((c ^ (e & 7)) << 3) + jl;
                Bh[idx] = hi; Bl[idx] = lo;
            }
        }
}

__global__ __launch_bounds__(256)
void msg_mfma_k(const u16* __restrict__ h_hi, const u16* __restrict__ h_lo,
                const int* __restrict__ row, const int* __restrict__ col,
                const u16* __restrict__ exg,
                const u16* __restrict__ W1m_h, const u16* __restrict__ W1m_l,
                const u16* __restrict__ W1x_h, const u16* __restrict__ W1x_l,
                const u16* __restrict__ W2_h,  const u16* __restrict__ W2_l,
                const u16* __restrict__ W3_h,  const u16* __restrict__ W3_l,
                const float* __restrict__ bm1, const float* __restrict__ bm2,
                const float* __restrict__ bm3,
                float* __restrict__ nm) {
    __shared__ u16 Ah[64 * 128], Al[64 * 128];
    __shared__ u16 Bh[64 * 128], Bl[64 * 128];
    __shared__ u16 exh[64 * 8],  exl[64 * 8];

    const int tid  = threadIdx.x;
    const int e0   = blockIdx.x * 64;
    const int lane = tid & 63;
    const int w    = tid >> 6;
    const int l15  = lane & 15;
    const int g    = lane >> 4;
    const int wn   = w * 32;

    // stage em = [h[row] | h[col]] hi/lo (swizzled)
    #pragma unroll
    for (int i = 0; i < 4; i++) {
        int idx = i * 256 + tid;            // 0..1023 -> (e, chunk)
        int e = idx >> 4, c = idx & 15;
        int node = (c < 8) ? row[e0 + e] : col[e0 + e];
        int off = node * 64 + (c & 7) * 8;
        int dst = (e * 16 + (c ^ (e & 7))) * 8;
        *(uint4*)(Ah + dst) = *(const uint4*)(h_hi + off);
        *(uint4*)(Al + dst) = *(const uint4*)(h_lo + off);
    }
    if (tid < 64) {
        uint4 v = *(const uint4*)(exg + (e0 + tid) * 8);
        uint4 vh, vl;
        vh.x = v.x; vh.y = v.y; vh.z = 0u; vh.w = 0u;
        vl.x = v.z; vl.y = v.w; vl.z = 0u; vl.w = 0u;
        *(uint4*)(exh + tid * 8) = vh;
        *(uint4*)(exl + tid * 8) = vl;
    }
    __syncthreads();

    h8_t zf;
    #pragma unroll
    for (int q = 0; q < 8; q++) zf[q] = (_Float16)0.0f;

    // ---- layer 1: [131]->[128] relu,  A(+ex) -> B ----
    {
        f32x4 accH[4][2], accC[4][2];
        layer_gemm3<2>(Ah, Al, W1m_h, W1m_l, bm1, wn, l15, g, accH, accC);
        h8_t axh[4], axl[4], bxh[2], bxl[2];
        #pragma unroll
        for (int jt = 0; jt < 2; jt++) {
            int off = (wn + jt * 16 + l15) * 8;
            bxh[jt] = (g == 0) ? *(const h8_t*)(W1x_h + off) : zf;
            bxl[jt] = (g == 0) ? *(const h8_t*)(W1x_l + off) : zf;
        }
        #pragma unroll
        for (int et = 0; et < 4; et++) {
            int off = (et * 16 + l15) * 8;
            axh[et] = (g == 0) ? *(const h8_t*)(exh + off) : zf;
            axl[et] = (g == 0) ? *(const h8_t*)(exl + off) : zf;
        }
        #pragma unroll
        for (int et = 0; et < 4; et++)
            #pragma unroll
            for (int jt = 0; jt < 2; jt++) {
                accH[et][jt] = MFMA(axh[et], bxh[jt], accH[et][jt]);
                accC[et][jt] = MFMA(axh[et], bxl[jt], accC[et][jt]);
                accC[et][jt] = MFMA(axl[et], bxh[jt], accC[et][jt]);
            }
        write_act2(Bh, Bl, accH, accC, wn, l15, g);
    }
    __syncthreads();

    // ---- layer 2: [128]->[128] relu,  B -> A ----
    {
        f32x4 accH[4][2], accC[4][2];
        layer_gemm3<2>(Bh, Bl, W2_h, W2_l, bm2, wn, l15, g, accH, accC);
        write_act2(Ah, Al, accH, accC, wn, l15, g);
    }
    __syncthreads();

    // ---- layer 3: [128]->[64],  A -> m_s (f32, aliases Bh) ----
    {
        const int wn3 = w * 16;
        f32x4 accH[4][1], accC[4][1];
        layer_gemm3<1>(Ah, Al, W3_h, W3_l, bm3, wn3, l15, g, accH, accC);
        float* m_s = (float*)Bh;            // 64*64 f32 == 16 KB == sizeof(Bh)
        #pragma unroll
        for (int et = 0; et < 4; et++)
            #pragma unroll
            for (int r = 0; r < 4; r++)
                m_s[(et * 16 + g * 4 + r) * 64 + wn3 + l15] =
                    accH[et][0][r] + accC[et][0][r] * LO_INV;
    }
    __syncthreads();

    // ---- scatter: rows sorted (np.unique) -> run-accumulate, few atomics ----
    {
        const float* m_s = (const float*)Bh;
        int d = tid & 63, q = tid >> 6;
        int ebeg = q * 16;
        float a = 0.f;
        int cur = row[e0 + ebeg];
        for (int e = ebeg; e < ebeg + 16; e++) {
            int rr = row[e0 + e];
            if (rr != cur) { atomicAdd(&nm[cur * 64 + d], a); a = 0.f; cur = rr; }
            a += m_s[e * 64 + d];
        }
        atomicAdd(&nm[cur * 64 + d], a);
    }
}

// ---------------- GRU (fp32 math, h kept as fp16 hi/lo pair) ----------------
// Also zeroes nm after consuming it (saves a per-step memset launch).
__global__ __launch_bounds__(256)
void gru_k(float* __restrict__ nm,
           u16* __restrict__ h_hi, u16* __restrict__ h_lo,
           const float* __restrict__ Wiht, const float* __restrict__ Whht,
           const float* __restrict__ b_ih, const float* __restrict__ b_hh) {
    __shared__ float nms[4][64], hs[4][64];
    int tid = threadIdx.x, g = tid >> 6, d = tid & 63;
    int n = blockIdx.x * 4 + g;
    nms[g][d] = nm[n * 64 + d];
    nm[n * 64 + d] = 0.f;                  // reset for next step's atomics
    hs[g][d]  = joinv(h_hi[n * 64 + d], h_lo[n * 64 + d]);
    __syncthreads();
    float ir = b_ih[d], iz = b_ih[64 + d], inn = b_ih[128 + d];
    float hr = b_hh[d], hz = b_hh[64 + d], hnn = b_hh[128 + d];
    for (int k = 0; k < 64; k++) {
        float nv = nms[g][k], hv = hs[g][k];
        const float* wi = Wiht + k * 192;
        const float* wh = Whht + k * 192;
        ir  = fmaf(nv, wi[d],       ir);
        iz  = fmaf(nv, wi[64 + d],  iz);
        inn = fmaf(nv, wi[128 + d], inn);
        hr  = fmaf(hv, wh[d],       hr);
        hz  = fmaf(hv, wh[64 + d],  hz);
        hnn = fmaf(hv, wh[128 + d], hnn);
    }
    float r  = 1.f / (1.f + expf(-(ir + hr)));
    float z  = 1.f / (1.f + expf(-(iz + hz)));
    float ng = tanhf(inn + r * hnn);
    float v  = (1.f - z) * ng + z * hs[g][d];
    u16 hi, lo; split2(v, hi, lo);
    h_hi[n * 64 + d] = hi;
    h_lo[n * 64 + d] = lo;
}

// ---------------- readout MLP + softmax ----------------
__global__ __launch_bounds__(256)
void readout_k(const u16* __restrict__ h_hi, const u16* __restrict__ h_lo,
               const float* __restrict__ Wr1t, const float* __restrict__ br1,
               const float* __restrict__ Wr2t, const float* __restrict__ br2,
               const float* __restrict__ Wr3,  const float* __restrict__ br3,
               float* __restrict__ out) {
    __shared__ float hs[4][64], r1s[4][128];
    int tid = threadIdx.x, g = tid >> 6, d = tid & 63;
    int n = blockIdx.x * 4 + g;
    hs[g][d] = joinv(h_hi[n * 64 + d], h_lo[n * 64 + d]);
    __syncthreads();
    float a0 = br1[d], a1 = br1[64 + d];
    for (int k = 0; k < 64; k++) {
        float v = hs[g][k];
        a0 = fmaf(v, Wr1t[k * 128 + d],      a0);
        a1 = fmaf(v, Wr1t[k * 128 + 64 + d], a1);
    }
    r1s[g][d] = fmaxf(a0, 0.f); r1s[g][64 + d] = fmaxf(a1, 0.f);
    __syncthreads();
    a0 = br2[d]; a1 = br2[64 + d];
    for (int k = 0; k < 128; k++) {
        float v = r1s[g][k];
        a0 = fmaf(v, Wr2t[k * 128 + d],      a0);
        a1 = fmaf(v, Wr2t[k * 128 + 64 + d], a1);
    }
    float q0 = fmaxf(a0, 0.f), q1 = fmaxf(a1, 0.f);
    float p0 = q0 * Wr3[d]       + q1 * Wr3[64 + d];
    float p1 = q0 * Wr3[128 + d] + q1 * Wr3[128 + 64 + d];
    #pragma unroll
    for (int off = 32; off > 0; off >>= 1) {
        p0 += __shfl_down(p0, off);
        p1 += __shfl_down(p1, off);
    }
    if (d == 0) {
        float l0 = p0 + br3[0], l1 = p1 + br3[1];
        float mx = fmaxf(l0, l1);
        float e0v = expf(l0 - mx), e1v = expf(l1 - mx), s = e0v + e1v;
        out[n * 2 + 0] = e0v / s;
        out[n * 2 + 1] = e1v / s;
        out[2 * N_NODES + n * 2 + 0] = l0;
        out[2 * N_NODES + n * 2 + 1] = l1;
    }
}

extern "C" void kernel_launch(void* const* d_in, const int* in_sizes, int n_in,
                              void* d_out, int out_size, void* d_ws, size_t ws_size,
                              hipStream_t stream) {
    const float* J    = (const float*)d_in[0];
    const float* b    = (const float*)d_in[1];
    const int*   row  = (const int*)d_in[2];
    const int*   col  = (const int*)d_in[3];
    const float* Wm1  = (const float*)d_in[4];
    const float* bm1  = (const float*)d_in[5];
    const float* Wm2  = (const float*)d_in[6];
    const float* bm2  = (const float*)d_in[7];
    const float* Wm3  = (const float*)d_in[8];
    const float* bm3  = (const float*)d_in[9];
    const float* W_ih = (const float*)d_in[10];
    const float* W_hh = (const float*)d_in[11];
    const float* b_ih = (const float*)d_in[12];
    const float* b_hh = (const float*)d_in[13];
    const float* Wr1  = (const float*)d_in[14];
    const float* br1  = (const float*)d_in[15];
    const float* Wr2  = (const float*)d_in[16];
    const float* br2  = (const float*)d_in[17];
    const float* Wr3  = (const float*)d_in[18];
    const float* br3  = (const float*)d_in[19];
    float* out = (float*)d_out;

    // fp32 regions
    float* ws   = (float*)d_ws;
    float* nm   = ws;  ws += N_NODES * 64;
    float* Wiht = ws;  ws += 64 * 192;
    float* Whht = ws;  ws += 64 * 192;
    float* Wr1t = ws;  ws += 64 * 128;
    float* Wr2t = ws;  ws += 128 * 128;
    // fp16-pair regions (u16 storage)
    u16* us    = (u16*)ws;
    u16* h_hi  = us;  us += N_NODES * 64;
    u16* h_lo  = us;  us += N_NODES * 64;
    u16* exg   = us;  us += N_EDGES * 8;
    u16* W1m_h = us;  us += 128 * 128;
    u16* W1m_l = us;  us += 128 * 128;
    u16* W1x_h = us;  us += 128 * 8;
    u16* W1x_l = us;  us += 128 * 8;
    u16* W2_h  = us;  us += 128 * 128;
    u16* W2_l  = us;  us += 128 * 128;
    u16* W3_h  = us;  us += 64 * 128;
    u16* W3_l  = us;  us += 64 * 128;

    prep_edges_k<<<(N_EDGES + 255) / 256, 256, 0, stream>>>(J, b, row, col, exg);
    convw_k<<<164, 256, 0, stream>>>(Wm1, Wm2, Wm3, W1m_h, W1m_l, W1x_h, W1x_l,
                                     W2_h, W2_l, W3_h, W3_l);
    transpose_k<<<(192 * 64 + 255) / 256, 256, 0, stream>>>(W_ih, Wiht, 192, 64);
    transpose_k<<<(192 * 64 + 255) / 256, 256, 0, stream>>>(W_hh, Whht, 192, 64);
    transpose_k<<<(128 * 64 + 255) / 256, 256, 0, stream>>>(Wr1, Wr1t, 128, 64);
    transpose_k<<<(128 * 128 + 255) / 256, 256, 0, stream>>>(Wr2, Wr2t, 128, 128);

    hipMemsetAsync(h_hi, 0, N_NODES * 64 * sizeof(u16), stream);
    hipMemsetAsync(h_lo, 0, N_NODES * 64 * sizeof(u16), stream);
    hipMemsetAsync(nm, 0, N_NODES * 64 * sizeof(float), stream);

    for (int s = 0; s < NSTEPS; s++) {
        msg_mfma_k<<<N_EDGES / 64, 256, 0, stream>>>(h_hi, h_lo, row, col, exg,
                                                     W1m_h, W1m_l, W1x_h, W1x_l,
                                                     W2_h, W2_l, W3_h, W3_l,
                                                     bm1, bm2, bm3, nm);
        gru_k<<<N_NODES / 4, 256, 0, stream>>>(nm, h_hi, h_lo, Wiht, Whht, b_ih, b_hh);
    }
    readout_k<<<N_NODES / 4, 256, 0, stream>>>(h_hi, h_lo, Wr1t, br1, Wr2t, br2,
                                               Wr3, br3, out);
}